// Round 15
// baseline (80.280 us; speedup 1.0000x reference)
//
#include <hip/hip_runtime.h>

typedef unsigned short u16;
typedef unsigned int u32;
typedef __attribute__((ext_vector_type(8))) short short8;
typedef __attribute__((ext_vector_type(4))) float f32x4;
typedef __attribute__((ext_vector_type(4))) unsigned short ushort4v;
typedef __attribute__((ext_vector_type(4))) float float4v;

// ---------- helpers ----------
__device__ __forceinline__ float bf2f(u16 u) {
    return __uint_as_float(((u32)u) << 16);
}
__device__ __forceinline__ u16 f2bf(float f) {
    u32 u = __float_as_uint(f);
    u += 0x7FFF + ((u >> 16) & 1);   // RNE
    return (u16)(u >> 16);
}
__device__ __forceinline__ short8 cvt8(float4 a, float4 b) {
    short8 r;
    r[0] = (short)f2bf(a.x); r[1] = (short)f2bf(a.y);
    r[2] = (short)f2bf(a.z); r[3] = (short)f2bf(a.w);
    r[4] = (short)f2bf(b.x); r[5] = (short)f2bf(b.y);
    r[6] = (short)f2bf(b.z); r[7] = (short)f2bf(b.w);
    return r;
}
// async global->LDS, 16B per lane; dst wave-uniform (HW adds lane*16)
__device__ __forceinline__ void stage16(const u16* g, u16* l) {
    __builtin_amdgcn_global_load_lds(
        (const __attribute__((address_space(1))) unsigned int*)g,
        (__attribute__((address_space(3))) unsigned int*)l, 16, 0, 0);
}

// ---------- K0: cvt+transpose+row-copy+colsum partials | Wv cvt | U_h = Wq_h^T Wk_h ----------
__global__ __launch_bounds__(256) void cvt_t(const float* __restrict__ x,
                                             u16* __restrict__ xT,
                                             u16* __restrict__ xb,
                                             float* __restrict__ sp2,
                                             const float* __restrict__ W,
                                             u16* __restrict__ wvb,
                                             u16* __restrict__ Ub) {
    __shared__ __align__(16) char smem[36864];
    const int bid = blockIdx.x;
    const int t = threadIdx.x;
    if (bid >= 1280) {   // U-compute: 128 blocks = h(8) x mt(4) x nt(4), K=64
        const int u = bid - 1280;
        const int h = u >> 4, mt = (u >> 2) & 3, ntt = u & 3;
        u16 (*At)[72] = (u16(*)[72])smem;              // [c1][d] K-major, pad 72
        u16 (*Bt)[72] = (u16(*)[72])(smem + 18432);    // [c2][d]
        const int d = t >> 2, cg = (t & 3) * 32;
        const float* wq = W + (size_t)(h * 64 + d) * 512 + mt * 128 + cg;
        const float* wk = W + (size_t)(512 + h * 64 + d) * 512 + ntt * 128 + cg;
#pragma unroll
        for (int j = 0; j < 32; j += 4) {
            float4 a = *(const float4*)(wq + j);
            float4 kk = *(const float4*)(wk + j);
            At[cg + j + 0][d] = f2bf(a.x); At[cg + j + 1][d] = f2bf(a.y);
            At[cg + j + 2][d] = f2bf(a.z); At[cg + j + 3][d] = f2bf(a.w);
            Bt[cg + j + 0][d] = f2bf(kk.x); Bt[cg + j + 1][d] = f2bf(kk.y);
            Bt[cg + j + 2][d] = f2bf(kk.z); Bt[cg + j + 3][d] = f2bf(kk.w);
        }
        __syncthreads();
        const int l = t & 63, wv = t >> 6;
        const int lr = l & 15, lk = (l >> 4) * 8;
        const int wm = (wv >> 1) * 64, wn = (wv & 1) * 64;
        f32x4 zz = {0.f, 0.f, 0.f, 0.f};
        f32x4 acc[4][4];
        for (int i = 0; i < 4; ++i)
            for (int j = 0; j < 4; ++j) acc[i][j] = zz;
#pragma unroll
        for (int k0 = 0; k0 < 64; k0 += 32) {
            short8 af[4], bfr[4];
#pragma unroll
            for (int mi = 0; mi < 4; ++mi)
                af[mi] = *(const short8*)(&At[wm + mi * 16 + lr][k0 + lk]);
#pragma unroll
            for (int ni = 0; ni < 4; ++ni)
                bfr[ni] = *(const short8*)(&Bt[wn + ni * 16 + lr][k0 + lk]);
#pragma unroll
            for (int mi = 0; mi < 4; ++mi)
#pragma unroll
                for (int ni = 0; ni < 4; ++ni)
                    acc[mi][ni] = __builtin_amdgcn_mfma_f32_16x16x32_bf16(
                        af[mi], bfr[ni], acc[mi][ni], 0, 0, 0);
        }
#pragma unroll
        for (int mi = 0; mi < 4; ++mi)
#pragma unroll
            for (int ni = 0; ni < 4; ++ni) {
                int col = ntt * 128 + wn + ni * 16 + lr;
#pragma unroll
                for (int j = 0; j < 4; ++j) {
                    int row = mt * 128 + wm + mi * 16 + (l >> 4) * 4 + j;
                    Ub[((size_t)(h * 512 + row)) * 512 + col] = f2bf(acc[mi][ni][j]);
                }
            }
        return;
    }
    if (bid >= 1024) {   // Wv fp32 -> bf16
        const int i = (bid - 1024) * 256 + t;
        float4v v = ((const float4v*)(W + 524288))[i];
        ushort4v r;
        r[0] = f2bf(v[0]); r[1] = f2bf(v[1]); r[2] = f2bf(v[2]); r[3] = f2bf(v[3]);
        ((ushort4v*)wvb)[i] = r;
        return;
    }
    u16 (*tile)[136] = (u16(*)[136])smem;   // [n][c], pad 8
    const int ct = bid & 3, nt = (bid >> 2) & 127, b = bid >> 9;
    const int r = t >> 2, c0 = (t & 3) * 32;
    const float* src = x + ((size_t)(b * 8192 + nt * 64 + r)) * 512 + ct * 128 + c0;
    short8 r8[4];
#pragma unroll
    for (int j = 0; j < 8; j += 2) {
        float4 v0 = *(const float4*)(src + j * 4);
        float4 v1 = *(const float4*)(src + j * 4 + 4);
        r8[j >> 1] = cvt8(v0, v1);
        *(short8*)(&tile[r][c0 + j * 4]) = r8[j >> 1];
    }
    // row-major bf16 copy
    u16* xbrow = xb + ((size_t)(b * 8192 + nt * 64 + r)) * 512 + ct * 128 + c0;
#pragma unroll
    for (int jj = 0; jj < 4; ++jj) *(short8*)(xbrow + jj * 8) = r8[jj];
    __syncthreads();
    const int c = t >> 1, half = t & 1;
    u16 vals[32];
    float psum = 0.f;
#pragma unroll
    for (int i = 0; i < 32; ++i) {
        vals[i] = tile[half * 32 + i][c];
        psum += bf2f(vals[i]);
    }
    u16* dst = xT + ((size_t)(b * 512 + ct * 128 + c)) * 8192 + nt * 64 + half * 32;
#pragma unroll
    for (int j = 0; j < 4; ++j)
        *(int4*)(dst + j * 8) = *(int4*)(&vals[j * 8]);
    psum += __shfl_xor(psum, 1);
    if ((t & 1) == 0)
        sp2[((size_t)(b * 128 + nt)) * 512 + ct * 128 + c] = psum;   // non-atomic partial
}

// ---------- shared GEMM core: 128x128 tile, BK=32, global_load_lds (proven r10) ----------
template <int STRIDE, int KLEN>
__device__ __forceinline__ void gemm_core(const u16* __restrict__ Ag,
                                          const u16* __restrict__ Bg,
                                          u16* As, u16* Bs, int t,
                                          f32x4 acc[4][4]) {
    const int wv = t >> 6, l = t & 63;
    const int lr = l & 15, lk = (l >> 4) * 8;
    const int wm = (wv >> 1) * 64, wn = (wv & 1) * 64;
    const int srow = l >> 2, scol = (l & 3) * 8;

    u16* Ad0 = As + (wv * 32) * 32;
    u16* Ad1 = As + (wv * 32 + 16) * 32;
    u16* Bd0 = Bs + (wv * 32) * 32;
    u16* Bd1 = Bs + (wv * 32 + 16) * 32;
    const u16* As0 = Ag + (size_t)(wv * 32 + srow) * STRIDE + scol;
    const u16* As1 = Ag + (size_t)(wv * 32 + 16 + srow) * STRIDE + scol;
    const u16* Bs0 = Bg + (size_t)(wv * 32 + srow) * STRIDE + scol;
    const u16* Bs1 = Bg + (size_t)(wv * 32 + 16 + srow) * STRIDE + scol;

    for (int k0 = 0; k0 < KLEN; k0 += 32) {
        stage16(As0 + k0, Ad0);
        stage16(As1 + k0, Ad1);
        stage16(Bs0 + k0, Bd0);
        stage16(Bs1 + k0, Bd1);
        __syncthreads();
        short8 af[4], bfr[4];
#pragma unroll
        for (int mi = 0; mi < 4; ++mi)
            af[mi] = *(const short8*)(As + (wm + mi * 16 + lr) * 32 + lk);
#pragma unroll
        for (int ni = 0; ni < 4; ++ni)
            bfr[ni] = *(const short8*)(Bs + (wn + ni * 16 + lr) * 32 + lk);
#pragma unroll
        for (int mi = 0; mi < 4; ++mi)
#pragma unroll
            for (int ni = 0; ni < 4; ++ni)
                acc[mi][ni] = __builtin_amdgcn_mfma_f32_16x16x32_bf16(
                    af[mi], bfr[ni], acc[mi][ni], 0, 0, 0);
        __syncthreads();
    }
}

// ---------- K1: symmetric syrk — 10 upper tiles per (b,ks); mirror via LDS transpose ----------
// 320 GEMM blocks + 4 ssum-reduce. XCD chunked swizzle: wid=(bid%8)*40+bid/8 (320%8==0);
// chunk of 40 = {b, 4 ks, all 10 pairs} -> 16 panel slices x 128KB = 2MB per XCD L2.
// Mirror tile (nt,mt) is the bitwise fp32 transpose of (mt,nt) (same n-order, commutative
// products) -> output bit-identical to the full 512-block version.
__global__ __launch_bounds__(256) void syrk(const u16* __restrict__ xT,
                                            u16* __restrict__ Spart,
                                            const float* __restrict__ sp2,
                                            float* __restrict__ ssum) {
    const int bid = blockIdx.x, t = threadIdx.x;
    if (bid >= 320) {   // reduce sp2 -> ssum
        const int idx = (bid - 320) * 256 + t;   // [0,1024)
        const int b = idx >> 9, c = idx & 511;
        float a = 0.f;
        for (int j = 0; j < 128; ++j) a += sp2[(size_t)(b * 128 + j) * 512 + c];
        ssum[idx] = a;
        return;
    }
    const int wid = (bid & 7) * 40 + (bid >> 3);   // bijective for 320 blocks
    const int p = wid % 10;
    const int ks = (wid / 10) & 15, b = wid / 160;
    // p -> upper-triangle pair (mt<=nt): (0,0..3),(1,1..3),(2,2..3),(3,3)
    int mt, nt;
    if (p < 4)      { mt = 0; nt = p; }
    else if (p < 7) { mt = 1; nt = p - 3; }
    else if (p < 9) { mt = 2; nt = p - 5; }
    else            { mt = 3; nt = 3; }

    __shared__ u16 As[128 * 32];
    __shared__ u16 Bs[128 * 32];
    __shared__ u16 Ts[64][136];   // transpose staging, pad 8
    const u16* Ag = xT + ((size_t)(b * 512 + mt * 128)) * 8192 + ks * 512;
    const u16* Bg = xT + ((size_t)(b * 512 + nt * 128)) * 8192 + ks * 512;

    f32x4 zz = {0.f, 0.f, 0.f, 0.f};
    f32x4 acc[4][4];
    for (int i = 0; i < 4; ++i)
        for (int j = 0; j < 4; ++j) acc[i][j] = zz;

    gemm_core<8192, 512>(Ag, Bg, As, Bs, t, acc);

    const int l = t & 63, wv = t >> 6;
    const int lr = l & 15;
    const int wm = (wv >> 1) * 64, wn = (wv & 1) * 64;
    u16* out = Spart + ((size_t)(b * 16 + ks)) * 262144;
#pragma unroll
    for (int mi = 0; mi < 4; ++mi)
#pragma unroll
        for (int ni = 0; ni < 4; ++ni) {
            int col = nt * 128 + wn + ni * 16 + lr;
#pragma unroll
            for (int j = 0; j < 4; ++j) {
                int row = mt * 128 + wm + mi * 16 + (l >> 4) * 4 + j;
                out[(size_t)row * 512 + col] = f2bf(acc[mi][ni][j]);
            }
        }

    if (mt != nt) {   // emit mirror tile (nt,mt) via LDS transpose, 2 chunks of 64 rows
#pragma unroll
        for (int ch = 0; ch < 2; ++ch) {
            __syncthreads();
            if ((wv >> 1) == ch) {   // waves holding rows [ch*64, ch*64+64)
#pragma unroll
                for (int mi = 0; mi < 4; ++mi)
#pragma unroll
                    for (int ni = 0; ni < 4; ++ni)
#pragma unroll
                        for (int j = 0; j < 4; ++j)
                            Ts[mi * 16 + (l >> 4) * 4 + j][wn + ni * 16 + lr] =
                                f2bf(acc[mi][ni][j]);
            }
            __syncthreads();
            const int n = t >> 1, mh = (t & 1) * 32;
            u16 buf[32];
#pragma unroll
            for (int i = 0; i < 32; ++i) buf[i] = Ts[mh + i][n];
            u16* d = out + (size_t)(nt * 128 + n) * 512 + mt * 128 + ch * 64 + mh;
#pragma unroll
            for (int q = 0; q < 4; ++q) *(int4*)(d + q * 8) = *(const int4*)(&buf[q * 8]);
        }
    }
}

// ---------- K2: reduce partials + centering -> S' bf16 (ushort2-vectorized, proven r11) ----------
__global__ __launch_bounds__(256) void reduceS(const u16* __restrict__ Spart,
                                               const float* __restrict__ s,
                                               u16* __restrict__ Sbf) {
    const int b = blockIdx.x >> 9, m = blockIdx.x & 511;
    const int t = threadIdx.x;
    const float sm = s[b * 512 + m] * (1.0f / 8192.0f);
    const int n0 = t * 2;
    float a0 = 0.f, a1 = 0.f;
#pragma unroll
    for (int ks = 0; ks < 16; ++ks) {
        u32 v = *(const u32*)(Spart + ((size_t)(b * 16 + ks)) * 262144 +
                              (size_t)m * 512 + n0);
        a0 += bf2f((u16)(v & 0xffff));
        a1 += bf2f((u16)(v >> 16));
    }
    a0 -= sm * s[b * 512 + n0];
    a1 -= sm * s[b * 512 + n0 + 1];
    u32 packed = (u32)f2bf(a0) | ((u32)f2bf(a1) << 16);
    *(u32*)(Sbf + (size_t)b * 262144 + (size_t)m * 512 + n0) = packed;
}

// ---------- K3: Ppart[b][ks] = Wv * S'_b (K-split x4, proven r4), fp32 partials ----------
__global__ __launch_bounds__(256) void pgemm(const u16* __restrict__ wvb,
                                             const u16* __restrict__ Sbf,
                                             float* __restrict__ Ppart) {
    __shared__ u16 As[128 * 32];
    __shared__ u16 Bs[128 * 32];
    const int t = threadIdx.x;
    const int nt = blockIdx.x & 3, mt = (blockIdx.x >> 2) & 3;
    const int ks = (blockIdx.x >> 4) & 3, b = blockIdx.x >> 6;
    const u16* Ag = wvb + (size_t)(mt * 128) * 512 + ks * 128;
    const u16* Bg = Sbf + (size_t)b * 262144 + (size_t)(nt * 128) * 512 + ks * 128;

    f32x4 zz = {0.f, 0.f, 0.f, 0.f};
    f32x4 acc[4][4];
    for (int i = 0; i < 4; ++i)
        for (int j = 0; j < 4; ++j) acc[i][j] = zz;

    gemm_core<512, 128>(Ag, Bg, As, Bs, t, acc);

    const int l = t & 63, wv = t >> 6;
    const int lr = l & 15;
    const int wm = (wv >> 1) * 64, wn = (wv & 1) * 64;
    float* out = Ppart + ((size_t)(b * 4 + ks)) * 262144;
#pragma unroll
    for (int mi = 0; mi < 4; ++mi)
#pragma unroll
        for (int ni = 0; ni < 4; ++ni) {
            int col = nt * 128 + wn + ni * 16 + lr;
#pragma unroll
            for (int j = 0; j < 4; ++j) {
                int row = mt * 128 + wm + mi * 16 + (l >> 4) * 4 + j;
                out[(size_t)row * 512 + col] = acc[mi][ni][j];
            }
        }
}

// ---------- K4: Wgpart[ks] = P_bh x U_h^T, with reduceP folded into A-staging (proven r14) ----------
__global__ __launch_bounds__(256) void wgg(const u16* __restrict__ Ub,
                                           const float* __restrict__ Ppart,
                                           float* __restrict__ Wgpart) {
    __shared__ u16 As[64 * 136];   // [he][k] pitch 136, 17.4KB
    __shared__ u16 Bs[128 * 32];
    const int ks = blockIdx.x & 3, ct = (blockIdx.x >> 2) & 3, bh = blockIdx.x >> 4;
    const int b = bh >> 3, h = bh & 7;
    const int t = threadIdx.x, wv = t >> 6, l = t & 63;
    const int lr = l & 15, lk = (l >> 4) * 8;
    const int wm = (wv >> 1) * 32, wn = (wv & 1) * 64;
    const int srow = l >> 2, scol = (l & 3) * 8;

    // ---- A staging: sum 4 Ppart slices (pks order 0..3 = old reduceP), cvt bf16 ----
    const float* Pb0 = Ppart + ((size_t)(b * 4)) * 262144 +
                       ((size_t)(h * 64)) * 512 + ks * 128;
#pragma unroll
    for (int i = 0; i < 8; ++i) {
        int idx = i * 1024 + t * 4;          // element index in [64][128]
        int r = idx >> 7, c = idx & 127;
        const float* p = Pb0 + (size_t)r * 512 + c;
        float4 s0 = *(const float4*)(p);
        float4 s1 = *(const float4*)(p + 262144);
        float4 s2 = *(const float4*)(p + 524288);
        float4 s3 = *(const float4*)(p + 786432);
        ushort4v r4v;
        r4v[0] = f2bf(s0.x + s1.x + s2.x + s3.x);
        r4v[1] = f2bf(s0.y + s1.y + s2.y + s3.y);
        r4v[2] = f2bf(s0.z + s1.z + s2.z + s3.z);
        r4v[3] = f2bf(s0.w + s1.w + s2.w + s3.w);
        *(ushort4v*)(&As[r * 136 + c]) = r4v;
    }

    const u16* Bg = Ub + (size_t)(h * 512 + ct * 128) * 512 + ks * 128;
    u16* Bd0 = Bs + (wv * 32) * 32;
    u16* Bd1 = Bs + (wv * 32 + 16) * 32;
    const u16* Bs0 = Bg + (size_t)(wv * 32 + srow) * 512 + scol;
    const u16* Bs1 = Bg + (size_t)(wv * 32 + 16 + srow) * 512 + scol;

    f32x4 zz = {0.f, 0.f, 0.f, 0.f};
    f32x4 acc[2][4];
    for (int i = 0; i < 2; ++i)
        for (int j = 0; j < 4; ++j) acc[i][j] = zz;

    __syncthreads();   // A resident before K-loop
    for (int k0 = 0; k0 < 128; k0 += 32) {
        stage16(Bs0 + k0, Bd0);
        stage16(Bs1 + k0, Bd1);
        __syncthreads();
        short8 af[2], bfr[4];
#pragma unroll
        for (int mi = 0; mi < 2; ++mi)
            af[mi] = *(const short8*)(As + (wm + mi * 16 + lr) * 136 + k0 + lk);
#pragma unroll
        for (int ni = 0; ni < 4; ++ni)
            bfr[ni] = *(const short8*)(Bs + (wn + ni * 16 + lr) * 32 + lk);
#pragma unroll
        for (int mi = 0; mi < 2; ++mi)
#pragma unroll
            for (int ni = 0; ni < 4; ++ni)
                acc[mi][ni] = __builtin_amdgcn_mfma_f32_16x16x32_bf16(
                    af[mi], bfr[ni], acc[mi][ni], 0, 0, 0);
        __syncthreads();
    }
#pragma unroll
    for (int mi = 0; mi < 2; ++mi)
#pragma unroll
        for (int ni = 0; ni < 4; ++ni) {
            int col = ct * 128 + wn + ni * 16 + lr;
#pragma unroll
            for (int j = 0; j < 4; ++j) {
                int row = wm + mi * 16 + (l >> 4) * 4 + j;   // he in [0,64)
                Wgpart[((size_t)(ks * 1024 + b * 512 + h * 64 + row)) * 512 + col] =
                    acc[mi][ni][j];
            }
        }
}

// ---------- K5: reduce Wgpart -> Wgb bf16 ----------
__global__ __launch_bounds__(256) void reduceW(const float* __restrict__ Wgpart,
                                               u16* __restrict__ Wgb) {
    int idx = blockIdx.x * 1024 + threadIdx.x;
    for (int r = 0; r < 4; ++r, idx += 256) {
        float acc = 0.f;
#pragma unroll
        for (int ks = 0; ks < 4; ++ks)
            acc += Wgpart[(size_t)ks * 524288 + idx];
        Wgb[idx] = f2bf(acc);
    }
}

// ---------- K6: z = scale/1024 + (x @ Wg)/1024, both operands bf16 staged ----------
__global__ __launch_bounds__(256) void out_z(const u16* __restrict__ xb,
                                             const u16* __restrict__ Wgb,
                                             float* __restrict__ z) {
    __shared__ u16 As[128 * 32];
    __shared__ u16 Bs[128 * 32];
    const int t = threadIdx.x;
    const int m0 = blockIdx.x * 128;
    const int b = blockIdx.x >> 6;
    const int n0 = blockIdx.y * 128;

    f32x4 zz = {0.f, 0.f, 0.f, 0.f};
    f32x4 acc[4][4];
    for (int i = 0; i < 4; ++i)
        for (int j = 0; j < 4; ++j) acc[i][j] = zz;

    gemm_core<512, 512>(xb + (size_t)m0 * 512,
                        Wgb + (size_t)b * 262144 + (size_t)n0 * 512, As, Bs, t, acc);

    const int l = t & 63, wv = t >> 6;
    const int lr = l & 15;
    const int wm = (wv >> 1) * 64, wn = (wv & 1) * 64;
#pragma unroll
    for (int mi = 0; mi < 4; ++mi)
#pragma unroll
        for (int ni = 0; ni < 4; ++ni) {
            int he = n0 + wn + ni * 16 + lr;
            int h = he >> 6, e = he & 63;
#pragma unroll
            for (int j = 0; j < 4; ++j) {
                int row = m0 + wm + mi * 16 + (l >> 4) * 4 + j;
                int nidx = row & 8191;
                z[((size_t)(b * 8 + h) * 8192 + nidx) * 64 + e] =
                    (acc[mi][ni][j] + 0.125f) * 0.0009765625f;
            }
        }
}

extern "C" void kernel_launch(void* const* d_in, const int* in_sizes, int n_in,
                              void* d_out, int out_size, void* d_ws, size_t ws_size,
                              hipStream_t stream) {
    const float* x = (const float*)d_in[0];   // [2,8192,512] fp32
    const float* W = (const float*)d_in[1];   // [1536,512] fp32
    float* z = (float*)d_out;                 // [2,8,8192,64] fp32

    char* ws = (char*)d_ws;
    u16* xT       = (u16*)(ws);                  // 16,777,216 B  [2][512][8192]
    u16* xb       = (u16*)(ws + 16777216);       // 16,777,216 B  [2][8192][512]
    u16* Spart    = (u16*)(ws + 33554432);       // 16,777,216 B  [2][16][512][512]
    u16* Sbf      = (u16*)(ws + 50331648);       //  1,048,576 B  [2][512][512]
    float* sp2    = (float*)(ws + 51380224);     //    524,288 B  [2][128][512]
    float* ssum   = (float*)(ws + 51904512);     //      4,096 B  [2][512]
    u16* wvb      = (u16*)(ws + 51908608);       //    524,288 B  [512][512]
    u16* Ub       = (u16*)(ws + 53481472);       //  4,194,304 B  [8][512][512]
    u16* Wgb      = (u16*)(ws + 57675776);       //  1,048,576 B  [2][512][512]
    float* Ppart  = (float*)(ws + 58724352);     //  8,388,608 B  [2][4][512][512]
    float* Wgpart = (float*)(ws + 67112960);     //  8,388,608 B  [4][2][512][512]

    cvt_t<<<1408, 256, 0, stream>>>(x, xT, xb, sp2, W, wvb, Ub);
    syrk<<<324, 256, 0, stream>>>(xT, Spart, sp2, ssum);
    reduceS<<<1024, 256, 0, stream>>>(Spart, ssum, Sbf);
    pgemm<<<128, 256, 0, stream>>>(wvb, Sbf, Ppart);
    wgg<<<256, 256, 0, stream>>>(Ub, Ppart, Wgpart);
    reduceW<<<512, 256, 0, stream>>>(Wgpart, Wgb);
    out_z<<<dim3(128, 4), 256, 0, stream>>>(xb, Wgb, z);
}

// Round 16
// 77.783 us; speedup vs baseline: 1.0321x; 1.0321x over previous
//
#include <hip/hip_runtime.h>

typedef unsigned short u16;
typedef unsigned int u32;
typedef __attribute__((ext_vector_type(8))) short short8;
typedef __attribute__((ext_vector_type(4))) float f32x4;
typedef __attribute__((ext_vector_type(4))) unsigned short ushort4v;
typedef __attribute__((ext_vector_type(4))) float float4v;

// ---------- helpers ----------
__device__ __forceinline__ float bf2f(u16 u) {
    return __uint_as_float(((u32)u) << 16);
}
__device__ __forceinline__ u16 f2bf(float f) {
    u32 u = __float_as_uint(f);
    u += 0x7FFF + ((u >> 16) & 1);   // RNE
    return (u16)(u >> 16);
}
__device__ __forceinline__ short8 cvt8(float4 a, float4 b) {
    short8 r;
    r[0] = (short)f2bf(a.x); r[1] = (short)f2bf(a.y);
    r[2] = (short)f2bf(a.z); r[3] = (short)f2bf(a.w);
    r[4] = (short)f2bf(b.x); r[5] = (short)f2bf(b.y);
    r[6] = (short)f2bf(b.z); r[7] = (short)f2bf(b.w);
    return r;
}
// async global->LDS, 16B per lane; dst wave-uniform (HW adds lane*16)
__device__ __forceinline__ void stage16(const u16* g, u16* l) {
    __builtin_amdgcn_global_load_lds(
        (const __attribute__((address_space(1))) unsigned int*)g,
        (__attribute__((address_space(3))) unsigned int*)l, 16, 0, 0);
}

// ---------- K0: cvt+transpose+row-copy+colsum partials | Wv cvt | U_h = Wq_h^T Wk_h ----------
__global__ __launch_bounds__(256) void cvt_t(const float* __restrict__ x,
                                             u16* __restrict__ xT,
                                             u16* __restrict__ xb,
                                             float* __restrict__ sp2,
                                             const float* __restrict__ W,
                                             u16* __restrict__ wvb,
                                             u16* __restrict__ Ub) {
    __shared__ __align__(16) char smem[36864];
    const int bid = blockIdx.x;
    const int t = threadIdx.x;
    if (bid >= 1280) {   // U-compute: 128 blocks = h(8) x mt(4) x nt(4), K=64
        const int u = bid - 1280;
        const int h = u >> 4, mt = (u >> 2) & 3, ntt = u & 3;
        u16 (*At)[72] = (u16(*)[72])smem;              // [c1][d] K-major, pad 72
        u16 (*Bt)[72] = (u16(*)[72])(smem + 18432);    // [c2][d]
        const int d = t >> 2, cg = (t & 3) * 32;
        const float* wq = W + (size_t)(h * 64 + d) * 512 + mt * 128 + cg;
        const float* wk = W + (size_t)(512 + h * 64 + d) * 512 + ntt * 128 + cg;
#pragma unroll
        for (int j = 0; j < 32; j += 4) {
            float4 a = *(const float4*)(wq + j);
            float4 kk = *(const float4*)(wk + j);
            At[cg + j + 0][d] = f2bf(a.x); At[cg + j + 1][d] = f2bf(a.y);
            At[cg + j + 2][d] = f2bf(a.z); At[cg + j + 3][d] = f2bf(a.w);
            Bt[cg + j + 0][d] = f2bf(kk.x); Bt[cg + j + 1][d] = f2bf(kk.y);
            Bt[cg + j + 2][d] = f2bf(kk.z); Bt[cg + j + 3][d] = f2bf(kk.w);
        }
        __syncthreads();
        const int l = t & 63, wv = t >> 6;
        const int lr = l & 15, lk = (l >> 4) * 8;
        const int wm = (wv >> 1) * 64, wn = (wv & 1) * 64;
        f32x4 zz = {0.f, 0.f, 0.f, 0.f};
        f32x4 acc[4][4];
        for (int i = 0; i < 4; ++i)
            for (int j = 0; j < 4; ++j) acc[i][j] = zz;
#pragma unroll
        for (int k0 = 0; k0 < 64; k0 += 32) {
            short8 af[4], bfr[4];
#pragma unroll
            for (int mi = 0; mi < 4; ++mi)
                af[mi] = *(const short8*)(&At[wm + mi * 16 + lr][k0 + lk]);
#pragma unroll
            for (int ni = 0; ni < 4; ++ni)
                bfr[ni] = *(const short8*)(&Bt[wn + ni * 16 + lr][k0 + lk]);
#pragma unroll
            for (int mi = 0; mi < 4; ++mi)
#pragma unroll
                for (int ni = 0; ni < 4; ++ni)
                    acc[mi][ni] = __builtin_amdgcn_mfma_f32_16x16x32_bf16(
                        af[mi], bfr[ni], acc[mi][ni], 0, 0, 0);
        }
#pragma unroll
        for (int mi = 0; mi < 4; ++mi)
#pragma unroll
            for (int ni = 0; ni < 4; ++ni) {
                int col = ntt * 128 + wn + ni * 16 + lr;
#pragma unroll
                for (int j = 0; j < 4; ++j) {
                    int row = mt * 128 + wm + mi * 16 + (l >> 4) * 4 + j;
                    Ub[((size_t)(h * 512 + row)) * 512 + col] = f2bf(acc[mi][ni][j]);
                }
            }
        return;
    }
    if (bid >= 1024) {   // Wv fp32 -> bf16
        const int i = (bid - 1024) * 256 + t;
        float4v v = ((const float4v*)(W + 524288))[i];
        ushort4v r;
        r[0] = f2bf(v[0]); r[1] = f2bf(v[1]); r[2] = f2bf(v[2]); r[3] = f2bf(v[3]);
        ((ushort4v*)wvb)[i] = r;
        return;
    }
    u16 (*tile)[136] = (u16(*)[136])smem;   // [n][c], pad 8
    const int ct = bid & 3, nt = (bid >> 2) & 127, b = bid >> 9;
    const int r = t >> 2, c0 = (t & 3) * 32;
    const float* src = x + ((size_t)(b * 8192 + nt * 64 + r)) * 512 + ct * 128 + c0;
    short8 r8[4];
#pragma unroll
    for (int j = 0; j < 8; j += 2) {
        float4 v0 = *(const float4*)(src + j * 4);
        float4 v1 = *(const float4*)(src + j * 4 + 4);
        r8[j >> 1] = cvt8(v0, v1);
        *(short8*)(&tile[r][c0 + j * 4]) = r8[j >> 1];
    }
    // row-major bf16 copy
    u16* xbrow = xb + ((size_t)(b * 8192 + nt * 64 + r)) * 512 + ct * 128 + c0;
#pragma unroll
    for (int jj = 0; jj < 4; ++jj) *(short8*)(xbrow + jj * 8) = r8[jj];
    __syncthreads();
    const int c = t >> 1, half = t & 1;
    u16 vals[32];
    float psum = 0.f;
#pragma unroll
    for (int i = 0; i < 32; ++i) {
        vals[i] = tile[half * 32 + i][c];
        psum += bf2f(vals[i]);
    }
    u16* dst = xT + ((size_t)(b * 512 + ct * 128 + c)) * 8192 + nt * 64 + half * 32;
#pragma unroll
    for (int j = 0; j < 4; ++j)
        *(int4*)(dst + j * 8) = *(int4*)(&vals[j * 8]);
    psum += __shfl_xor(psum, 1);
    if ((t & 1) == 0)
        sp2[((size_t)(b * 128 + nt)) * 512 + ct * 128 + c] = psum;   // non-atomic partial
}

// ---------- shared GEMM core: 128x128 tile, BK=32, global_load_lds (proven r10) ----------
template <int STRIDE, int KLEN>
__device__ __forceinline__ void gemm_core(const u16* __restrict__ Ag,
                                          const u16* __restrict__ Bg,
                                          u16* As, u16* Bs, int t,
                                          f32x4 acc[4][4]) {
    const int wv = t >> 6, l = t & 63;
    const int lr = l & 15, lk = (l >> 4) * 8;
    const int wm = (wv >> 1) * 64, wn = (wv & 1) * 64;
    const int srow = l >> 2, scol = (l & 3) * 8;

    u16* Ad0 = As + (wv * 32) * 32;
    u16* Ad1 = As + (wv * 32 + 16) * 32;
    u16* Bd0 = Bs + (wv * 32) * 32;
    u16* Bd1 = Bs + (wv * 32 + 16) * 32;
    const u16* As0 = Ag + (size_t)(wv * 32 + srow) * STRIDE + scol;
    const u16* As1 = Ag + (size_t)(wv * 32 + 16 + srow) * STRIDE + scol;
    const u16* Bs0 = Bg + (size_t)(wv * 32 + srow) * STRIDE + scol;
    const u16* Bs1 = Bg + (size_t)(wv * 32 + 16 + srow) * STRIDE + scol;

    for (int k0 = 0; k0 < KLEN; k0 += 32) {
        stage16(As0 + k0, Ad0);
        stage16(As1 + k0, Ad1);
        stage16(Bs0 + k0, Bd0);
        stage16(Bs1 + k0, Bd1);
        __syncthreads();
        short8 af[4], bfr[4];
#pragma unroll
        for (int mi = 0; mi < 4; ++mi)
            af[mi] = *(const short8*)(As + (wm + mi * 16 + lr) * 32 + lk);
#pragma unroll
        for (int ni = 0; ni < 4; ++ni)
            bfr[ni] = *(const short8*)(Bs + (wn + ni * 16 + lr) * 32 + lk);
#pragma unroll
        for (int mi = 0; mi < 4; ++mi)
#pragma unroll
            for (int ni = 0; ni < 4; ++ni)
                acc[mi][ni] = __builtin_amdgcn_mfma_f32_16x16x32_bf16(
                    af[mi], bfr[ni], acc[mi][ni], 0, 0, 0);
        __syncthreads();
    }
}

// ---------- K1: syrk partials (16 chunks of 512 rows) + ssum reduce ----------
// XCD chunked swizzle (T1/m204): wid=(bid%8)*64+bid/8
__global__ __launch_bounds__(256) void syrk(const u16* __restrict__ xT,
                                            u16* __restrict__ Spart,
                                            const float* __restrict__ sp2,
                                            float* __restrict__ ssum) {
    const int bid = blockIdx.x, t = threadIdx.x;
    if (bid >= 512) {   // reduce sp2 -> ssum
        const int idx = (bid - 512) * 256 + t;   // [0,1024)
        const int b = idx >> 9, c = idx & 511;
        float a = 0.f;
        for (int j = 0; j < 128; ++j) a += sp2[(size_t)(b * 128 + j) * 512 + c];
        ssum[idx] = a;
        return;
    }
    const int wid = (bid & 7) * 64 + (bid >> 3);   // bijective for 512 blocks
    __shared__ u16 As[128 * 32];
    __shared__ u16 Bs[128 * 32];
    const int nt = wid & 3, mt = (wid >> 2) & 3;
    const int ks = (wid >> 4) & 15, b = wid >> 8;
    const u16* Ag = xT + ((size_t)(b * 512 + mt * 128)) * 8192 + ks * 512;
    const u16* Bg = xT + ((size_t)(b * 512 + nt * 128)) * 8192 + ks * 512;

    f32x4 zz = {0.f, 0.f, 0.f, 0.f};
    f32x4 acc[4][4];
    for (int i = 0; i < 4; ++i)
        for (int j = 0; j < 4; ++j) acc[i][j] = zz;

    gemm_core<8192, 512>(Ag, Bg, As, Bs, t, acc);

    const int l = t & 63, wv = t >> 6;
    const int lr = l & 15;
    const int wm = (wv >> 1) * 64, wn = (wv & 1) * 64;
    u16* out = Spart + ((size_t)(b * 16 + ks)) * 262144;
#pragma unroll
    for (int mi = 0; mi < 4; ++mi)
#pragma unroll
        for (int ni = 0; ni < 4; ++ni) {
            int col = nt * 128 + wn + ni * 16 + lr;
#pragma unroll
            for (int j = 0; j < 4; ++j) {
                int row = mt * 128 + wm + mi * 16 + (l >> 4) * 4 + j;
                out[(size_t)row * 512 + col] = f2bf(acc[mi][ni][j]);
            }
        }
}

// ---------- K2: reduce partials + centering -> S' bf16 (ushort2-vectorized, proven r11) ----------
__global__ __launch_bounds__(256) void reduceS(const u16* __restrict__ Spart,
                                               const float* __restrict__ s,
                                               u16* __restrict__ Sbf) {
    const int b = blockIdx.x >> 9, m = blockIdx.x & 511;
    const int t = threadIdx.x;
    const float sm = s[b * 512 + m] * (1.0f / 8192.0f);
    const int n0 = t * 2;
    float a0 = 0.f, a1 = 0.f;
#pragma unroll
    for (int ks = 0; ks < 16; ++ks) {
        u32 v = *(const u32*)(Spart + ((size_t)(b * 16 + ks)) * 262144 +
                              (size_t)m * 512 + n0);
        a0 += bf2f((u16)(v & 0xffff));
        a1 += bf2f((u16)(v >> 16));
    }
    a0 -= sm * s[b * 512 + n0];
    a1 -= sm * s[b * 512 + n0 + 1];
    u32 packed = (u32)f2bf(a0) | ((u32)f2bf(a1) << 16);
    *(u32*)(Sbf + (size_t)b * 262144 + (size_t)m * 512 + n0) = packed;
}

// ---------- K3: Ppart[b][ks] = Wv * S'_b (K-split x4, proven r4), fp32 partials ----------
__global__ __launch_bounds__(256) void pgemm(const u16* __restrict__ wvb,
                                             const u16* __restrict__ Sbf,
                                             float* __restrict__ Ppart) {
    __shared__ u16 As[128 * 32];
    __shared__ u16 Bs[128 * 32];
    const int t = threadIdx.x;
    const int nt = blockIdx.x & 3, mt = (blockIdx.x >> 2) & 3;
    const int ks = (blockIdx.x >> 4) & 3, b = blockIdx.x >> 6;
    const u16* Ag = wvb + (size_t)(mt * 128) * 512 + ks * 128;
    const u16* Bg = Sbf + (size_t)b * 262144 + (size_t)(nt * 128) * 512 + ks * 128;

    f32x4 zz = {0.f, 0.f, 0.f, 0.f};
    f32x4 acc[4][4];
    for (int i = 0; i < 4; ++i)
        for (int j = 0; j < 4; ++j) acc[i][j] = zz;

    gemm_core<512, 128>(Ag, Bg, As, Bs, t, acc);

    const int l = t & 63, wv = t >> 6;
    const int lr = l & 15;
    const int wm = (wv >> 1) * 64, wn = (wv & 1) * 64;
    float* out = Ppart + ((size_t)(b * 4 + ks)) * 262144;
#pragma unroll
    for (int mi = 0; mi < 4; ++mi)
#pragma unroll
        for (int ni = 0; ni < 4; ++ni) {
            int col = nt * 128 + wn + ni * 16 + lr;
#pragma unroll
            for (int j = 0; j < 4; ++j) {
                int row = mt * 128 + wm + mi * 16 + (l >> 4) * 4 + j;
                out[(size_t)row * 512 + col] = acc[mi][ni][j];
            }
        }
}

// ---------- K4: Wgpart[ks] = P_bh x U_h^T, with reduceP folded into A-staging (proven r14) ----------
__global__ __launch_bounds__(256) void wgg(const u16* __restrict__ Ub,
                                           const float* __restrict__ Ppart,
                                           float* __restrict__ Wgpart) {
    __shared__ u16 As[64 * 136];   // [he][k] pitch 136, 17.4KB
    __shared__ u16 Bs[128 * 32];
    const int ks = blockIdx.x & 3, ct = (blockIdx.x >> 2) & 3, bh = blockIdx.x >> 4;
    const int b = bh >> 3, h = bh & 7;
    const int t = threadIdx.x, wv = t >> 6, l = t & 63;
    const int lr = l & 15, lk = (l >> 4) * 8;
    const int wm = (wv >> 1) * 32, wn = (wv & 1) * 64;
    const int srow = l >> 2, scol = (l & 3) * 8;

    // ---- A staging: sum 4 Ppart slices (pks order 0..3 = old reduceP), cvt bf16 ----
    const float* Pb0 = Ppart + ((size_t)(b * 4)) * 262144 +
                       ((size_t)(h * 64)) * 512 + ks * 128;
#pragma unroll
    for (int i = 0; i < 8; ++i) {
        int idx = i * 1024 + t * 4;          // element index in [64][128]
        int r = idx >> 7, c = idx & 127;
        const float* p = Pb0 + (size_t)r * 512 + c;
        float4 s0 = *(const float4*)(p);
        float4 s1 = *(const float4*)(p + 262144);
        float4 s2 = *(const float4*)(p + 524288);
        float4 s3 = *(const float4*)(p + 786432);
        ushort4v r4v;
        r4v[0] = f2bf(s0.x + s1.x + s2.x + s3.x);
        r4v[1] = f2bf(s0.y + s1.y + s2.y + s3.y);
        r4v[2] = f2bf(s0.z + s1.z + s2.z + s3.z);
        r4v[3] = f2bf(s0.w + s1.w + s2.w + s3.w);
        *(ushort4v*)(&As[r * 136 + c]) = r4v;
    }

    const u16* Bg = Ub + (size_t)(h * 512 + ct * 128) * 512 + ks * 128;
    u16* Bd0 = Bs + (wv * 32) * 32;
    u16* Bd1 = Bs + (wv * 32 + 16) * 32;
    const u16* Bs0 = Bg + (size_t)(wv * 32 + srow) * 512 + scol;
    const u16* Bs1 = Bg + (size_t)(wv * 32 + 16 + srow) * 512 + scol;

    f32x4 zz = {0.f, 0.f, 0.f, 0.f};
    f32x4 acc[2][4];
    for (int i = 0; i < 2; ++i)
        for (int j = 0; j < 4; ++j) acc[i][j] = zz;

    __syncthreads();   // A resident before K-loop
    for (int k0 = 0; k0 < 128; k0 += 32) {
        stage16(Bs0 + k0, Bd0);
        stage16(Bs1 + k0, Bd1);
        __syncthreads();
        short8 af[2], bfr[4];
#pragma unroll
        for (int mi = 0; mi < 2; ++mi)
            af[mi] = *(const short8*)(As + (wm + mi * 16 + lr) * 136 + k0 + lk);
#pragma unroll
        for (int ni = 0; ni < 4; ++ni)
            bfr[ni] = *(const short8*)(Bs + (wn + ni * 16 + lr) * 32 + lk);
#pragma unroll
        for (int mi = 0; mi < 2; ++mi)
#pragma unroll
            for (int ni = 0; ni < 4; ++ni)
                acc[mi][ni] = __builtin_amdgcn_mfma_f32_16x16x32_bf16(
                    af[mi], bfr[ni], acc[mi][ni], 0, 0, 0);
        __syncthreads();
    }
#pragma unroll
    for (int mi = 0; mi < 2; ++mi)
#pragma unroll
        for (int ni = 0; ni < 4; ++ni) {
            int col = ct * 128 + wn + ni * 16 + lr;
#pragma unroll
            for (int j = 0; j < 4; ++j) {
                int row = wm + mi * 16 + (l >> 4) * 4 + j;   // he in [0,64)
                Wgpart[((size_t)(ks * 1024 + b * 512 + h * 64 + row)) * 512 + col] =
                    acc[mi][ni][j];
            }
        }
}

// ---------- K5: reduce Wgpart -> Wgb bf16 ----------
__global__ __launch_bounds__(256) void reduceW(const float* __restrict__ Wgpart,
                                               u16* __restrict__ Wgb) {
    int idx = blockIdx.x * 1024 + threadIdx.x;
    for (int r = 0; r < 4; ++r, idx += 256) {
        float acc = 0.f;
#pragma unroll
        for (int ks = 0; ks < 4; ++ks)
            acc += Wgpart[(size_t)ks * 524288 + idx];
        Wgb[idx] = f2bf(acc);
    }
}

// ---------- K6: z = scale/1024 + (x @ Wg)/1024, both operands bf16 staged ----------
__global__ __launch_bounds__(256) void out_z(const u16* __restrict__ xb,
                                             const u16* __restrict__ Wgb,
                                             float* __restrict__ z) {
    __shared__ u16 As[128 * 32];
    __shared__ u16 Bs[128 * 32];
    const int t = threadIdx.x;
    const int m0 = blockIdx.x * 128;
    const int b = blockIdx.x >> 6;
    const int n0 = blockIdx.y * 128;

    f32x4 zz = {0.f, 0.f, 0.f, 0.f};
    f32x4 acc[4][4];
    for (int i = 0; i < 4; ++i)
        for (int j = 0; j < 4; ++j) acc[i][j] = zz;

    gemm_core<512, 512>(xb + (size_t)m0 * 512,
                        Wgb + (size_t)b * 262144 + (size_t)n0 * 512, As, Bs, t, acc);

    const int l = t & 63, wv = t >> 6;
    const int lr = l & 15;
    const int wm = (wv >> 1) * 64, wn = (wv & 1) * 64;
#pragma unroll
    for (int mi = 0; mi < 4; ++mi)
#pragma unroll
        for (int ni = 0; ni < 4; ++ni) {
            int he = n0 + wn + ni * 16 + lr;
            int h = he >> 6, e = he & 63;
#pragma unroll
            for (int j = 0; j < 4; ++j) {
                int row = m0 + wm + mi * 16 + (l >> 4) * 4 + j;
                int nidx = row & 8191;
                z[((size_t)(b * 8 + h) * 8192 + nidx) * 64 + e] =
                    (acc[mi][ni][j] + 0.125f) * 0.0009765625f;
            }
        }
}

extern "C" void kernel_launch(void* const* d_in, const int* in_sizes, int n_in,
                              void* d_out, int out_size, void* d_ws, size_t ws_size,
                              hipStream_t stream) {
    const float* x = (const float*)d_in[0];   // [2,8192,512] fp32
    const float* W = (const float*)d_in[1];   // [1536,512] fp32
    float* z = (float*)d_out;                 // [2,8,8192,64] fp32

    char* ws = (char*)d_ws;
    u16* xT       = (u16*)(ws);                  // 16,777,216 B  [2][512][8192]
    u16* xb       = (u16*)(ws + 16777216);       // 16,777,216 B  [2][8192][512]
    u16* Spart    = (u16*)(ws + 33554432);       // 16,777,216 B  [2][16][512][512]
    u16* Sbf      = (u16*)(ws + 50331648);       //  1,048,576 B  [2][512][512]
    float* sp2    = (float*)(ws + 51380224);     //    524,288 B  [2][128][512]
    float* ssum   = (float*)(ws + 51904512);     //      4,096 B  [2][512]
    u16* wvb      = (u16*)(ws + 51908608);       //    524,288 B  [512][512]
    u16* Ub       = (u16*)(ws + 53481472);       //  4,194,304 B  [8][512][512]
    u16* Wgb      = (u16*)(ws + 57675776);       //  1,048,576 B  [2][512][512]
    float* Ppart  = (float*)(ws + 58724352);     //  8,388,608 B  [2][4][512][512]
    float* Wgpart = (float*)(ws + 67112960);     //  8,388,608 B  [4][2][512][512]

    cvt_t<<<1408, 256, 0, stream>>>(x, xT, xb, sp2, W, wvb, Ub);
    syrk<<<516, 256, 0, stream>>>(xT, Spart, sp2, ssum);
    reduceS<<<1024, 256, 0, stream>>>(Spart, ssum, Sbf);
    pgemm<<<128, 256, 0, stream>>>(wvb, Sbf, Ppart);
    wgg<<<256, 256, 0, stream>>>(Ub, Ppart, Wgpart);
    reduceW<<<512, 256, 0, stream>>>(Wgpart, Wgb);
    out_z<<<dim3(128, 4), 256, 0, stream>>>(xb, Wgb, z);
}